// Round 16
// baseline (141.533 us; speedup 1.0000x reference)
//
#include <hip/hip_runtime.h>

#define IH 512
#define IW 512
#define OH 510
#define OW 510
#define NB 32
#define KO 16
#define OHW (OH * OW)
#define PPB 4              // planes per block (o-quarter)
#define LO 1020            // floats per plane-region in LDS (2 rows x 510)
#define NBLK (NB * (OH / 2) * 4)   // 32640
#define CPX (NBLK / 8)     // 4080 logical blocks per XCD chunk

typedef float f32x4 __attribute__((ext_vector_type(4)));
typedef float f32x2 __attribute__((ext_vector_type(2)));

// R16 = R15 with (1) PPB 8->4 + launch_bounds(256,8): 8 blocks/CU, finer
// generation interleave so some block is always in its drain phase while
// others load/compute (R15 residual = exposed phase heads), and (2) T1
// bijective XCD-chunk swizzle (32640%8==0): the 4 o-quarters of a tile and
// neighboring row-pairs (which share x rows) land on the SAME XCD -> x
// re-reads served by that XCD's 4MB L2 instead of bouncing to L3.
// Plain stores (R15's win). VGPR ~50 < 64 budget (watch counter for spill).
__global__ __launch_bounds__(256, 8) void conv3x3_k16_kernel(
    const float* __restrict__ x,
    const float* __restrict__ k,
    float* __restrict__ out)
{
    __shared__ float lds[PPB * LO];   // 16,320 B

    // XCD swizzle: physical bid pb -> logical lb; consecutive lb share one XCD.
    const int pb = blockIdx.x;
    const int lb = (pb & 7) * CPX + (pb >> 3);

    const int oq   = lb & 3;                  // filter quarter: planes 4*oq..
    const int tile = lb >> 2;
    const int n  = tile / (OH / 2);           // image
    const int i0 = (tile - n * (OH / 2)) * 2; // even base row
    const int t  = threadIdx.x;
    const int half = t >> 7;                  // row within pair
    const int tt = t & 127;
    const int i  = i0 + half;                 // output row
    const bool tail = (tt == 127);

    // Even rows: j=4tt (tail 508); odd rows: j=4tt+2 (tail 0).
    int j;
    if ((i & 1) == 0) j = tail ? 508 : 4 * tt;
    else              j = tail ? 0   : 4 * tt + 2;

    const float* xr = x + ((size_t)n * IH + i) * IW + j;

    // Phase 1: load 3 rows x 6 cols (tail: 3 x 4), 8B-aligned float2s.
    float xv[3][6];
#pragma unroll
    for (int r = 0; r < 3; ++r) {
        const float2 a = *reinterpret_cast<const float2*>(xr + r * IW);
        const float2 b = *reinterpret_cast<const float2*>(xr + r * IW + 2);
        xv[r][0] = a.x; xv[r][1] = a.y; xv[r][2] = b.x; xv[r][3] = b.y;
        if (!tail) {
            const float2 c = *reinterpret_cast<const float2*>(xr + r * IW + 4);
            xv[r][4] = c.x; xv[r][5] = c.y;
        } else {
            xv[r][4] = 0.0f; xv[r][5] = 0.0f;
        }
    }

    // Phase 2: FMA for 4 planes, deposit into LDS.
    const int lbase = half * OW + j;
#pragma unroll
    for (int ol = 0; ol < PPB; ++ol) {
        const int o = PPB * oq + ol;
        float a0 = 0.f, a1 = 0.f, a2 = 0.f, a3 = 0.f;
#pragma unroll
        for (int r = 0; r < 3; ++r)
#pragma unroll
            for (int c = 0; c < 3; ++c) {
                const float kv = k[(o * 3 + r) * 3 + c];  // uniform -> s_load
                a0 = fmaf(xv[r][c],     kv, a0);
                a1 = fmaf(xv[r][c + 1], kv, a1);
                a2 = fmaf(xv[r][c + 2], kv, a2);
                a3 = fmaf(xv[r][c + 3], kv, a3);
            }
        float* lp = &lds[ol * LO + lbase];
        f32x2 v0; v0[0] = a0; v0[1] = a1;
        *reinterpret_cast<f32x2*>(lp) = v0;
        if (!tail) {
            f32x2 v1; v1[0] = a2; v1[1] = a3;
            *reinterpret_cast<f32x2*>(lp + 2) = v1;
        }
    }

    __syncthreads();

    // Phase 3: stream out (plain stores -> L2 write-combining).
    if (t < 255) {
        float* ob = out + (((size_t)(n * KO + PPB * oq)) * OH + i0) * OW;
        const int f = 4 * t;
#pragma unroll
        for (int ol = 0; ol < PPB; ++ol) {
            const f32x4 v = *reinterpret_cast<const f32x4*>(&lds[ol * LO + f]);
            *reinterpret_cast<f32x4*>(ob + (size_t)ol * OHW + f) = v;
        }
    }
}

extern "C" void kernel_launch(void* const* d_in, const int* in_sizes, int n_in,
                              void* d_out, int out_size, void* d_ws, size_t ws_size,
                              hipStream_t stream) {
    const float* x   = (const float*)d_in[0];
    const float* ker = (const float*)d_in[1];
    float* out       = (float*)d_out;

    dim3 grid(NBLK);   // 32640 blocks: (image, row-pair) x o-quarter
    dim3 block(256);
    conv3x3_k16_kernel<<<grid, block, 0, stream>>>(x, ker, out);
}

// Round 17
// 120.099 us; speedup vs baseline: 1.1785x; 1.1785x over previous
//
#include <hip/hip_runtime.h>

#define IH 512
#define IW 512
#define OH 510
#define OW 510
#define NB 32
#define KO 16
#define OHW (OH * OW)
#define PPB 8              // planes per block
#define LO 1020            // floats per plane-region in LDS (2 rows x 510)
#define NBLK (NB * (OH / 2) * 2)   // 16320
#define CPX (NBLK / 8)     // 2040 logical blocks per XCD chunk

typedef float f32x4 __attribute__((ext_vector_type(4)));
typedef float f32x2 __attribute__((ext_vector_type(2)));

// R17 = R15 (champion, 118.4us) + ONE change: bijective XCD-chunk swizzle
// (16320 % 8 == 0). Consecutive logical blocks — the two o-halves of a tile
// and neighboring row-pairs, which share x rows — now land on the SAME XCD,
// so x re-reads are served by that XCD's 4MB L2 (per-XCD working set = 4
// images = 4MB) instead of bouncing through L3 every generation.
// Everything else byte-identical to R15 (PPB 8, plain stores, 4 blocks/CU).
__global__ __launch_bounds__(256, 4) void conv3x3_k16_kernel(
    const float* __restrict__ x,
    const float* __restrict__ k,
    float* __restrict__ out)
{
    __shared__ float lds[PPB * LO];   // 32,640 B

    // XCD swizzle: physical pb -> logical lb; consecutive lb share one XCD.
    const int pb = blockIdx.x;
    const int lb = (pb & 7) * CPX + (pb >> 3);

    const int oh   = lb & 1;                  // filter half: planes 8*oh..
    const int tile = lb >> 1;
    const int n  = tile / (OH / 2);           // image
    const int i0 = (tile - n * (OH / 2)) * 2; // even base row
    const int t  = threadIdx.x;
    const int half = t >> 7;                  // row within pair
    const int tt = t & 127;
    const int i  = i0 + half;                 // output row
    const bool tail = (tt == 127);

    // Even rows: j=4tt (tail 508); odd rows: j=4tt+2 (tail 0).
    int j;
    if ((i & 1) == 0) j = tail ? 508 : 4 * tt;
    else              j = tail ? 0   : 4 * tt + 2;

    const float* xr = x + ((size_t)n * IH + i) * IW + j;

    // Phase 1: load 3 rows x 6 cols (tail: 3 x 4), 8B-aligned float2s.
    float xv[3][6];
#pragma unroll
    for (int r = 0; r < 3; ++r) {
        const float2 a = *reinterpret_cast<const float2*>(xr + r * IW);
        const float2 b = *reinterpret_cast<const float2*>(xr + r * IW + 2);
        xv[r][0] = a.x; xv[r][1] = a.y; xv[r][2] = b.x; xv[r][3] = b.y;
        if (!tail) {
            const float2 c = *reinterpret_cast<const float2*>(xr + r * IW + 4);
            xv[r][4] = c.x; xv[r][5] = c.y;
        } else {
            xv[r][4] = 0.0f; xv[r][5] = 0.0f;
        }
    }

    // Phase 2: FMA for 8 planes, deposit into LDS.
    const int lbase = half * OW + j;
#pragma unroll
    for (int ol = 0; ol < PPB; ++ol) {
        const int o = PPB * oh + ol;
        float a0 = 0.f, a1 = 0.f, a2 = 0.f, a3 = 0.f;
#pragma unroll
        for (int r = 0; r < 3; ++r)
#pragma unroll
            for (int c = 0; c < 3; ++c) {
                const float kv = k[(o * 3 + r) * 3 + c];  // uniform -> s_load
                a0 = fmaf(xv[r][c],     kv, a0);
                a1 = fmaf(xv[r][c + 1], kv, a1);
                a2 = fmaf(xv[r][c + 2], kv, a2);
                a3 = fmaf(xv[r][c + 3], kv, a3);
            }
        float* lp = &lds[ol * LO + lbase];
        f32x2 v0; v0[0] = a0; v0[1] = a1;
        *reinterpret_cast<f32x2*>(lp) = v0;
        if (!tail) {
            f32x2 v1; v1[0] = a2; v1[1] = a3;
            *reinterpret_cast<f32x2*>(lp + 2) = v1;
        }
    }

    __syncthreads();

    // Phase 3: stream out (plain stores -> L2 write-combining).
    if (t < 255) {
        float* ob = out + (((size_t)(n * KO + PPB * oh)) * OH + i0) * OW;
        const int f = 4 * t;
#pragma unroll
        for (int ol = 0; ol < PPB; ++ol) {
            const f32x4 v = *reinterpret_cast<const f32x4*>(&lds[ol * LO + f]);
            *reinterpret_cast<f32x4*>(ob + (size_t)ol * OHW + f) = v;
        }
    }
}

extern "C" void kernel_launch(void* const* d_in, const int* in_sizes, int n_in,
                              void* d_out, int out_size, void* d_ws, size_t ws_size,
                              hipStream_t stream) {
    const float* x   = (const float*)d_in[0];
    const float* ker = (const float*)d_in[1];
    float* out       = (float*)d_out;

    dim3 grid(NBLK);   // 16320 blocks: (image, row-pair) x o-half
    dim3 block(256);
    conv3x3_k16_kernel<<<grid, block, 0, stream>>>(x, ker, out);
}